// Round 6
// baseline (204.065 us; speedup 1.0000x reference)
//
#include <hip/hip_runtime.h>

// ---------------------------------------------------------------------------
// Compile-time Wigner-3j (real basis) construction — constexpr port of the
// reference Python so all CG coefficients become literal immediates.
// ---------------------------------------------------------------------------

struct CD { double re, im; };
constexpr CD cmul(CD a, CD b) { return {a.re * b.re - a.im * b.im, a.re * b.im + a.im * b.re}; }
constexpr CD cmulr(CD a, double b) { return {a.re * b, a.im * b}; }
constexpr CD cadd(CD a, CD b) { return {a.re + b.re, a.im + b.im}; }
constexpr CD cconj(CD a) { return {a.re, -a.im}; }

constexpr double cfact(int n) {
    double r = 1.0;
    for (int i = 2; i <= n; ++i) r *= (double)i;
    return r;
}

constexpr double csqrt_(double x) {
    if (x <= 0.0) return 0.0;
    double g = x > 1.0 ? x : 1.0;
    for (int i = 0; i < 64; ++i) g = 0.5 * (g + x / g);
    return g;
}

constexpr double cg_su2(int j1, int j2, int j3, int m1, int m2, int m3) {
    if (m3 != m1 + m2) return 0.0;
    int vmin = -j1 + j2 + m3;
    if (-j1 + m1 > vmin) vmin = -j1 + m1;
    if (0 > vmin) vmin = 0;
    int vmax = j2 + j3 + m1;
    if (j3 - j1 + j2 < vmax) vmax = j3 - j1 + j2;
    if (j3 + m3 < vmax) vmax = j3 + m3;
    double pref = (2.0 * j3 + 1.0) *
        (cfact(j3 + j1 - j2) * cfact(j3 - j1 + j2) * cfact(j1 + j2 - j3) *
         cfact(j3 + m3) * cfact(j3 - m3)) /
        (cfact(j1 + j2 + j3 + 1) * cfact(j1 - m1) * cfact(j1 + m1) *
         cfact(j2 - m2) * cfact(j2 + m2));
    double s = 0.0;
    for (int v = vmin; v <= vmax; ++v) {
        double t = (cfact(j2 + j3 + m1 - v) * cfact(j1 - m1 + v)) /
                   (cfact(v) * cfact(j3 - j1 + j2 - v) * cfact(j3 + m3 - v) *
                    cfact(v + j1 - j2 - m3));
        if ((v + j2 + m2) & 1) s -= t; else s += t;
    }
    return csqrt_(pref) * s;
}

constexpr void fillQ(CD (&Q)[7][7], int l) {
    for (int a = 0; a < 7; ++a)
        for (int b = 0; b < 7; ++b) Q[a][b] = CD{0.0, 0.0};
    const double is2 = 1.0 / csqrt_(2.0);
    for (int m = -l; m < 0; ++m) {
        Q[l + m][l - m] = CD{is2, 0.0};
        Q[l + m][l + m] = CD{0.0, -is2};
    }
    Q[l][l] = CD{1.0, 0.0};
    for (int m = 1; m <= l; ++m) {
        double sg = (m & 1) ? -1.0 : 1.0;
        Q[l + m][l + m] = CD{sg * is2, 0.0};
        Q[l + m][l - m] = CD{0.0, sg * is2};
    }
    CD f = (l == 0) ? CD{1.0, 0.0} : (l == 1) ? CD{0.0, -1.0}
         : (l == 2) ? CD{-1.0, 0.0} : CD{0.0, 1.0};
    for (int a = 0; a < 2 * l + 1; ++a)
        for (int b = 0; b < 2 * l + 1; ++b) Q[a][b] = cmul(f, Q[a][b]);
}

template <int L1, int L2, int L3>
struct W3J { float c[2 * L1 + 1][2 * L2 + 1][2 * L3 + 1]; };

template <int L1, int L2, int L3>
constexpr W3J<L1, L2, L3> make_w3j() {
    constexpr int N1 = 2 * L1 + 1, N2 = 2 * L2 + 1, N3 = 2 * L3 + 1;
    double Cc[7][7][7] = {};
    for (int m1 = -L1; m1 <= L1; ++m1)
        for (int m2 = -L2; m2 <= L2; ++m2) {
            int m3 = m1 + m2;
            if (m3 >= -L3 && m3 <= L3)
                Cc[L1 + m1][L2 + m2][L3 + m3] = cg_su2(L1, L2, L3, m1, m2, m3);
        }
    CD Q1[7][7] = {}, Q2[7][7] = {}, Q3[7][7] = {};
    fillQ(Q1, L1); fillQ(Q2, L2); fillQ(Q3, L3);
    CD T1[7][7][7] = {};
    for (int j = 0; j < N1; ++j)
        for (int k = 0; k < N2; ++k)
            for (int n = 0; n < N3; ++n) {
                CD s{0.0, 0.0};
                for (int i = 0; i < N1; ++i) s = cadd(s, cmulr(Q1[i][j], Cc[i][k][n]));
                T1[j][k][n] = s;
            }
    CD T2[7][7][7] = {};
    for (int j = 0; j < N1; ++j)
        for (int l = 0; l < N2; ++l)
            for (int n = 0; n < N3; ++n) {
                CD s{0.0, 0.0};
                for (int k = 0; k < N2; ++k) s = cadd(s, cmul(Q2[k][l], T1[j][k][n]));
                T2[j][l][n] = s;
            }
    double R[7][7][7] = {};
    double ss = 0.0;
    for (int j = 0; j < N1; ++j)
        for (int l = 0; l < N2; ++l)
            for (int m = 0; m < N3; ++m) {
                CD s{0.0, 0.0};
                for (int n = 0; n < N3; ++n) s = cadd(s, cmul(cconj(Q3[n][m]), T2[j][l][n]));
                R[j][l][m] = s.re;
                ss += s.re * s.re;
            }
    double scale = csqrt_((double)(2 * L3 + 1)) / csqrt_(ss);
    W3J<L1, L2, L3> w{};
    for (int i = 0; i < N1; ++i)
        for (int j = 0; j < N2; ++j)
            for (int k = 0; k < N3; ++k)
                w.c[i][j][k] = (float)(R[i][j][k] * scale);
    return w;
}

// ---------------------------------------------------------------------------
// Kernel — one thread per (e, float2 pair), x loaded per-l1-group so peak
// live VGPR fits the <=64 bucket -> 32 waves/CU AND 8B-wide accesses.
// ---------------------------------------------------------------------------

#define E_TOT 16384
#define C_TOT 96
#define DIM1 16
#define DIM2 16
#define DIM_OUT 99
#define CP (C_TOT / 2)  // 48 float2 groups per row

using f2 = __attribute__((ext_vector_type(2))) float;
using f4 = __attribute__((ext_vector_type(4))) float;

// One tensor-product instruction. xv holds only this l1-group's rows (index from 0).
template <int L1, int L2, int L3, int O2, int KOFF>
__device__ __forceinline__ void tp_ins(const f2 (&xv)[2 * L1 + 1], const float (&yv)[DIM2],
                                       float* __restrict__ oute) {
    constexpr W3J<L1, L2, L3> w = make_w3j<L1, L2, L3>();
    f2 acc[2 * L3 + 1];
#pragma unroll
    for (int k = 0; k < 2 * L3 + 1; ++k) acc[k] = (f2)0.f;
#pragma unroll
    for (int i = 0; i < 2 * L1 + 1; ++i) {
#pragma unroll
        for (int j = 0; j < 2 * L2 + 1; ++j) {
            const f2 q = xv[i] * yv[O2 + j];  // DCE'd if all k coeffs are zero
#pragma unroll
            for (int k = 0; k < 2 * L3 + 1; ++k) {
                const float cv = w.c[i][j][k];  // literal; zero entries pruned
                if (cv != 0.0f) acc[k] += cv * q;
            }
        }
    }
#pragma unroll
    for (int k = 0; k < 2 * L3 + 1; ++k)
        *reinterpret_cast<f2*>(oute + (size_t)(KOFF + k) * C_TOT) = acc[k];
}

template <int L1, int O1>
__device__ __forceinline__ void load_rows(const float* __restrict__ xe, f2 (&xv)[2 * L1 + 1]) {
#pragma unroll
    for (int i = 0; i < 2 * L1 + 1; ++i)
        xv[i] = *reinterpret_cast<const f2*>(xe + (size_t)(O1 + i) * C_TOT);
}

__global__ __launch_bounds__(256, 8) void tp_kernel(const float* __restrict__ x,
                                                    const float* __restrict__ y,
                                                    float* __restrict__ out) {
    const int t = blockIdx.x * 256 + threadIdx.x;
    const int e = t / CP;
    const int c2 = t - e * CP;

    const float* xe = x + (size_t)e * (DIM1 * C_TOT) + 2 * c2;
    float* oute = out + (size_t)e * (DIM_OUT * C_TOT) + 2 * c2;

    // y: 16 floats per e, shared by 48 lanes -> cached vector loads
    float yv[DIM2];
    const f4* yp = reinterpret_cast<const f4*>(y + (size_t)e * DIM2);
#pragma unroll
    for (int j = 0; j < 4; ++j) {
        const f4 tq = yp[j];
        yv[4 * j + 0] = tq.x; yv[4 * j + 1] = tq.y;
        yv[4 * j + 2] = tq.z; yv[4 * j + 3] = tq.w;
    }

    // Per-l1-group: load that group's rows, run its instructions, release.
    // Peak live xv = 7 x f2 = 14 VGPR -> total ~55-60, fits the 64 bucket.
    {   // l1 = 0 (row 0)
        f2 xv[1];
        load_rows<0, 0>(xe, xv);
        tp_ins<0, 0, 0, 0, 0>(xv, yv, oute);
        tp_ins<0, 1, 1, 1, 1>(xv, yv, oute);
        tp_ins<0, 2, 2, 4, 4>(xv, yv, oute);
        tp_ins<0, 3, 3, 9, 9>(xv, yv, oute);
    }
    {   // l1 = 1 (rows 1..3)
        f2 xv[3];
        load_rows<1, 1>(xe, xv);
        tp_ins<1, 0, 1, 0, 16>(xv, yv, oute);
        tp_ins<1, 1, 0, 1, 19>(xv, yv, oute);
        tp_ins<1, 1, 2, 1, 20>(xv, yv, oute);
        tp_ins<1, 2, 1, 4, 25>(xv, yv, oute);
        tp_ins<1, 2, 3, 4, 28>(xv, yv, oute);
        tp_ins<1, 3, 2, 9, 35>(xv, yv, oute);
    }
    {   // l1 = 2 (rows 4..8)
        f2 xv[5];
        load_rows<2, 4>(xe, xv);
        tp_ins<2, 0, 2, 0, 40>(xv, yv, oute);
        tp_ins<2, 1, 1, 1, 45>(xv, yv, oute);
        tp_ins<2, 1, 3, 1, 48>(xv, yv, oute);
        tp_ins<2, 2, 0, 4, 55>(xv, yv, oute);
        tp_ins<2, 2, 2, 4, 56>(xv, yv, oute);
        tp_ins<2, 3, 1, 9, 61>(xv, yv, oute);
        tp_ins<2, 3, 3, 9, 64>(xv, yv, oute);
    }
    {   // l1 = 3 (rows 9..15)
        f2 xv[7];
        load_rows<3, 9>(xe, xv);
        tp_ins<3, 0, 3, 0, 71>(xv, yv, oute);
        tp_ins<3, 1, 2, 1, 78>(xv, yv, oute);
        tp_ins<3, 2, 1, 4, 83>(xv, yv, oute);
        tp_ins<3, 2, 3, 4, 86>(xv, yv, oute);
        tp_ins<3, 3, 0, 9, 93>(xv, yv, oute);
        tp_ins<3, 3, 2, 9, 94>(xv, yv, oute);
    }
}

extern "C" void kernel_launch(void* const* d_in, const int* in_sizes, int n_in,
                              void* d_out, int out_size, void* d_ws, size_t ws_size,
                              hipStream_t stream) {
    (void)in_sizes; (void)n_in; (void)d_ws; (void)ws_size; (void)out_size;
    const float* x = (const float*)d_in[0];
    const float* y = (const float*)d_in[1];
    float* out = (float*)d_out;
    const int total_threads = E_TOT * CP;  // 786432
    const int block = 256;
    const int grid = total_threads / block;  // 3072
    hipLaunchKernelGGL(tp_kernel, dim3(grid), dim3(block), 0, stream, x, y, out);
}

// Round 7
// 120.851 us; speedup vs baseline: 1.6886x; 1.6886x over previous
//
#include <hip/hip_runtime.h>

// ---------------------------------------------------------------------------
// Compile-time Wigner-3j (real basis) construction — constexpr port of the
// reference Python so all CG coefficients become literal immediates.
// ---------------------------------------------------------------------------

struct CD { double re, im; };
constexpr CD cmul(CD a, CD b) { return {a.re * b.re - a.im * b.im, a.re * b.im + a.im * b.re}; }
constexpr CD cmulr(CD a, double b) { return {a.re * b, a.im * b}; }
constexpr CD cadd(CD a, CD b) { return {a.re + b.re, a.im + b.im}; }
constexpr CD cconj(CD a) { return {a.re, -a.im}; }

constexpr double cfact(int n) {
    double r = 1.0;
    for (int i = 2; i <= n; ++i) r *= (double)i;
    return r;
}

constexpr double csqrt_(double x) {
    if (x <= 0.0) return 0.0;
    double g = x > 1.0 ? x : 1.0;
    for (int i = 0; i < 64; ++i) g = 0.5 * (g + x / g);
    return g;
}

constexpr double cg_su2(int j1, int j2, int j3, int m1, int m2, int m3) {
    if (m3 != m1 + m2) return 0.0;
    int vmin = -j1 + j2 + m3;
    if (-j1 + m1 > vmin) vmin = -j1 + m1;
    if (0 > vmin) vmin = 0;
    int vmax = j2 + j3 + m1;
    if (j3 - j1 + j2 < vmax) vmax = j3 - j1 + j2;
    if (j3 + m3 < vmax) vmax = j3 + m3;
    double pref = (2.0 * j3 + 1.0) *
        (cfact(j3 + j1 - j2) * cfact(j3 - j1 + j2) * cfact(j1 + j2 - j3) *
         cfact(j3 + m3) * cfact(j3 - m3)) /
        (cfact(j1 + j2 + j3 + 1) * cfact(j1 - m1) * cfact(j1 + m1) *
         cfact(j2 - m2) * cfact(j2 + m2));
    double s = 0.0;
    for (int v = vmin; v <= vmax; ++v) {
        double t = (cfact(j2 + j3 + m1 - v) * cfact(j1 - m1 + v)) /
                   (cfact(v) * cfact(j3 - j1 + j2 - v) * cfact(j3 + m3 - v) *
                    cfact(v + j1 - j2 - m3));
        if ((v + j2 + m2) & 1) s -= t; else s += t;
    }
    return csqrt_(pref) * s;
}

constexpr void fillQ(CD (&Q)[7][7], int l) {
    for (int a = 0; a < 7; ++a)
        for (int b = 0; b < 7; ++b) Q[a][b] = CD{0.0, 0.0};
    const double is2 = 1.0 / csqrt_(2.0);
    for (int m = -l; m < 0; ++m) {
        Q[l + m][l - m] = CD{is2, 0.0};
        Q[l + m][l + m] = CD{0.0, -is2};
    }
    Q[l][l] = CD{1.0, 0.0};
    for (int m = 1; m <= l; ++m) {
        double sg = (m & 1) ? -1.0 : 1.0;
        Q[l + m][l + m] = CD{sg * is2, 0.0};
        Q[l + m][l - m] = CD{0.0, sg * is2};
    }
    CD f = (l == 0) ? CD{1.0, 0.0} : (l == 1) ? CD{0.0, -1.0}
         : (l == 2) ? CD{-1.0, 0.0} : CD{0.0, 1.0};
    for (int a = 0; a < 2 * l + 1; ++a)
        for (int b = 0; b < 2 * l + 1; ++b) Q[a][b] = cmul(f, Q[a][b]);
}

template <int L1, int L2, int L3>
struct W3J { float c[2 * L1 + 1][2 * L2 + 1][2 * L3 + 1]; };

template <int L1, int L2, int L3>
constexpr W3J<L1, L2, L3> make_w3j() {
    constexpr int N1 = 2 * L1 + 1, N2 = 2 * L2 + 1, N3 = 2 * L3 + 1;
    double Cc[7][7][7] = {};
    for (int m1 = -L1; m1 <= L1; ++m1)
        for (int m2 = -L2; m2 <= L2; ++m2) {
            int m3 = m1 + m2;
            if (m3 >= -L3 && m3 <= L3)
                Cc[L1 + m1][L2 + m2][L3 + m3] = cg_su2(L1, L2, L3, m1, m2, m3);
        }
    CD Q1[7][7] = {}, Q2[7][7] = {}, Q3[7][7] = {};
    fillQ(Q1, L1); fillQ(Q2, L2); fillQ(Q3, L3);
    CD T1[7][7][7] = {};
    for (int j = 0; j < N1; ++j)
        for (int k = 0; k < N2; ++k)
            for (int n = 0; n < N3; ++n) {
                CD s{0.0, 0.0};
                for (int i = 0; i < N1; ++i) s = cadd(s, cmulr(Q1[i][j], Cc[i][k][n]));
                T1[j][k][n] = s;
            }
    CD T2[7][7][7] = {};
    for (int j = 0; j < N1; ++j)
        for (int l = 0; l < N2; ++l)
            for (int n = 0; n < N3; ++n) {
                CD s{0.0, 0.0};
                for (int k = 0; k < N2; ++k) s = cadd(s, cmul(Q2[k][l], T1[j][k][n]));
                T2[j][l][n] = s;
            }
    double R[7][7][7] = {};
    double ss = 0.0;
    for (int j = 0; j < N1; ++j)
        for (int l = 0; l < N2; ++l)
            for (int m = 0; m < N3; ++m) {
                CD s{0.0, 0.0};
                for (int n = 0; n < N3; ++n) s = cadd(s, cmul(cconj(Q3[n][m]), T2[j][l][n]));
                R[j][l][m] = s.re;
                ss += s.re * s.re;
            }
    double scale = csqrt_((double)(2 * L3 + 1)) / csqrt_(ss);
    W3J<L1, L2, L3> w{};
    for (int i = 0; i < N1; ++i)
        for (int j = 0; j < N2; ++j)
            for (int k = 0; k < N3; ++k)
                w.c[i][j][k] = (float)(R[i][j][k] * scale);
    return w;
}

// ---------------------------------------------------------------------------
// Kernel — R4 structure (one thread per (e, channel), ~60 VGPR, 32 waves/CU)
// with ONLY the output stores switched to nontemporal (L2-bypass hint).
// ---------------------------------------------------------------------------

#define E_TOT 16384
#define C_TOT 96
#define DIM1 16
#define DIM2 16
#define DIM_OUT 99

using f4 = __attribute__((ext_vector_type(4))) float;

template <int L1, int L2, int L3, int O1, int O2, int KOFF>
__device__ __forceinline__ void tp_ins(const float (&xv)[DIM1], const float (&yv)[DIM2],
                                       float* __restrict__ oute) {
    constexpr W3J<L1, L2, L3> w = make_w3j<L1, L2, L3>();
    float acc[2 * L3 + 1];
#pragma unroll
    for (int k = 0; k < 2 * L3 + 1; ++k) acc[k] = 0.f;
#pragma unroll
    for (int i = 0; i < 2 * L1 + 1; ++i) {
#pragma unroll
        for (int j = 0; j < 2 * L2 + 1; ++j) {
            const float q = xv[O1 + i] * yv[O2 + j];  // DCE'd if all k coeffs zero
#pragma unroll
            for (int k = 0; k < 2 * L3 + 1; ++k) {
                const float cv = w.c[i][j][k];  // literal; zero entries pruned
                if (cv != 0.0f) acc[k] += cv * q;
            }
        }
    }
#pragma unroll
    for (int k = 0; k < 2 * L3 + 1; ++k)
        __builtin_nontemporal_store(acc[k], oute + (size_t)(KOFF + k) * C_TOT);
}

__global__ __launch_bounds__(256, 8) void tp_kernel(const float* __restrict__ x,
                                                    const float* __restrict__ y,
                                                    float* __restrict__ out) {
    const int t = blockIdx.x * 256 + threadIdx.x;
    const int e = t / C_TOT;
    const int c = t - e * C_TOT;

    const float* xe = x + (size_t)e * (DIM1 * C_TOT) + c;

    // All 16 x loads issued up front: independent dword loads, full MLP.
    float xv[DIM1];
#pragma unroll
    for (int i = 0; i < DIM1; ++i) xv[i] = xe[(size_t)i * C_TOT];

    // y: 16 floats per e, shared by 96 lanes -> cached vector loads
    float yv[DIM2];
    const f4* yp = reinterpret_cast<const f4*>(y + (size_t)e * DIM2);
#pragma unroll
    for (int j = 0; j < 4; ++j) {
        const f4 tq = yp[j];
        yv[4 * j + 0] = tq.x; yv[4 * j + 1] = tq.y;
        yv[4 * j + 2] = tq.z; yv[4 * j + 3] = tq.w;
    }

    float* oute = out + (size_t)e * (DIM_OUT * C_TOT) + c;

    // instruction list: (l1,l2,l3,o1,o2,koff) in reference order
    tp_ins<0, 0, 0, 0, 0, 0>(xv, yv, oute);
    tp_ins<0, 1, 1, 0, 1, 1>(xv, yv, oute);
    tp_ins<0, 2, 2, 0, 4, 4>(xv, yv, oute);
    tp_ins<0, 3, 3, 0, 9, 9>(xv, yv, oute);
    tp_ins<1, 0, 1, 1, 0, 16>(xv, yv, oute);
    tp_ins<1, 1, 0, 1, 1, 19>(xv, yv, oute);
    tp_ins<1, 1, 2, 1, 1, 20>(xv, yv, oute);
    tp_ins<1, 2, 1, 1, 4, 25>(xv, yv, oute);
    tp_ins<1, 2, 3, 1, 4, 28>(xv, yv, oute);
    tp_ins<1, 3, 2, 1, 9, 35>(xv, yv, oute);
    tp_ins<2, 0, 2, 4, 0, 40>(xv, yv, oute);
    tp_ins<2, 1, 1, 4, 1, 45>(xv, yv, oute);
    tp_ins<2, 1, 3, 4, 1, 48>(xv, yv, oute);
    tp_ins<2, 2, 0, 4, 4, 55>(xv, yv, oute);
    tp_ins<2, 2, 2, 4, 4, 56>(xv, yv, oute);
    tp_ins<2, 3, 1, 4, 9, 61>(xv, yv, oute);
    tp_ins<2, 3, 3, 4, 9, 64>(xv, yv, oute);
    tp_ins<3, 0, 3, 9, 0, 71>(xv, yv, oute);
    tp_ins<3, 1, 2, 9, 1, 78>(xv, yv, oute);
    tp_ins<3, 2, 1, 9, 4, 83>(xv, yv, oute);
    tp_ins<3, 2, 3, 9, 4, 86>(xv, yv, oute);
    tp_ins<3, 3, 0, 9, 9, 93>(xv, yv, oute);
    tp_ins<3, 3, 2, 9, 9, 94>(xv, yv, oute);
}

extern "C" void kernel_launch(void* const* d_in, const int* in_sizes, int n_in,
                              void* d_out, int out_size, void* d_ws, size_t ws_size,
                              hipStream_t stream) {
    (void)in_sizes; (void)n_in; (void)d_ws; (void)ws_size; (void)out_size;
    const float* x = (const float*)d_in[0];
    const float* y = (const float*)d_in[1];
    float* out = (float*)d_out;
    const int total_threads = E_TOT * C_TOT;  // 1572864
    const int block = 256;
    const int grid = total_threads / block;   // 6144
    hipLaunchKernelGGL(tp_kernel, dim3(grid), dim3(block), 0, stream, x, y, out);
}